// Round 8
// baseline (993.385 us; speedup 1.0000x reference)
//
#include <hip/hip_runtime.h>
#include <stdint.h>

#define N_ROWS 32768
#define K_CB   8192
#define D_DIM  512
#define TAU    0.07f
#define BM     128
#define BK     32
#define NKT    256

typedef __attribute__((ext_vector_type(8))) short bf16x8;
typedef __attribute__((ext_vector_type(4))) float f32x4;

__device__ __forceinline__ unsigned short f2bf(float f) {
    unsigned u = __builtin_bit_cast(unsigned, f);
    u += 0x7FFFu + ((u >> 16) & 1u);          // round-to-nearest-even
    return (unsigned short)(u >> 16);
}

__device__ __forceinline__ void glds16(const unsigned short* g, unsigned short* l) {
    __builtin_amdgcn_global_load_lds(
        (const __attribute__((address_space(1))) unsigned int*)g,
        (__attribute__((address_space(3))) unsigned int*)l, 16, 0, 0);
}

__device__ __forceinline__ unsigned cvtpk(float a, float b) {
    unsigned r;
    asm("v_cvt_pk_bf16_f32 %0, %1, %2" : "=v"(r) : "v"(a), "v"(b));
    return r;
}

__device__ __forceinline__ void pl32swapf(float& a, float& b) {
    asm volatile("v_permlane32_swap_b32 %0, %1" : "+v"(a), "+v"(b));
}
__device__ __forceinline__ void pl16swapf(float& a, float& b) {
    asm volatile("v_permlane16_swap_b32 %0, %1" : "+v"(a), "+v"(b));
}

// lgkm-only barrier (T4): sx/px visibility without draining the glds prefetch queue
__device__ __forceinline__ void barrier_lgkm() {
    asm volatile("s_waitcnt lgkmcnt(0)" ::: "memory");
    __builtin_amdgcn_s_barrier();
    __builtin_amdgcn_sched_barrier(0);
}

// codebook fp32 [K][512] -> two pre-swizzled bf16 arrays of 16B chunks per 32-row tile:
//  rm_sw: chunk c = cbl*64 + (dc ^ (cbl&7))        holds C[tile cb=cbl][d = dc*8 .. +7]
//  t_sw : chunk c = (d*4 + cbc) ^ ((d>>1)&7)       holds C[tile cb=cbc*8+e][d], e=0..7
__global__ __launch_bounds__(512) void prep_codebook(const float* __restrict__ cb,
                                                     unsigned short* __restrict__ rm_sw,
                                                     unsigned short* __restrict__ t_sw) {
    __shared__ unsigned short tile[32 * 512];     // row-major [cbl][d]
    const int j = blockIdx.x, t = threadIdx.x;
    const float2* src = (const float2*)(cb + (size_t)j * (BK * D_DIM));
    unsigned* t32 = (unsigned*)tile;
    #pragma unroll
    for (int it = 0; it < 16; ++it) {
        int e2 = it * 512 + t;
        float2 v = src[e2];
        t32[e2] = (unsigned)f2bf(v.x) | ((unsigned)f2bf(v.y) << 16);
    }
    __syncthreads();
    uint4* rmd = (uint4*)rm_sw + (size_t)j * 2048;
    uint4* twd = (uint4*)t_sw + (size_t)j * 2048;
    #pragma unroll
    for (int it = 0; it < 4; ++it) {
        int L = it * 512 + t;
        int cbl = L >> 6, dc = L & 63;
        int c = cbl * 64 + (dc ^ (cbl & 7));
        rmd[c] = *(const uint4*)&tile[cbl * 512 + dc * 8];
    }
    #pragma unroll
    for (int it = 0; it < 4; ++it) {
        int M = it * 512 + t;
        int d = M >> 2, cbc = M & 3;
        int c = (d * 4 + cbc) ^ ((d >> 1) & 7);
        unsigned short tmp[8];
        #pragma unroll
        for (int e = 0; e < 8; ++e) tmp[e] = tile[(cbc * 8 + e) * 512 + d];
        twd[c] = *(const uint4*)tmp;
    }
}

// 16-wave variant of the r4 K-split structure: 1024 threads, 8 pairs x 16 rows.
// Per-wave state halves (afrag 32 VGPR, acc 64) -> 4 waves/SIMD for latency hiding.
// Sync structure = r4's proven {Bsx lgkm, B1 lgkm, B2 __syncthreads}; math order-identical.
__global__ __launch_bounds__(1024, 4) void cbmap_main(const float* __restrict__ x,
                                                      const unsigned short* __restrict__ rm_sw,
                                                      const unsigned short* __restrict__ t_sw,
                                                      float* __restrict__ out) {
    __shared__ unsigned short s_rm[2][16384];   // 2 x 32 KB, swizzled cb-major tile
    __shared__ unsigned short s_ct[2][16384];   // 2 x 32 KB, swizzled d-major tile
    __shared__ float s_sx[8][2][256];           // 16 KB [pair][dst e][lane*4]
    __shared__ unsigned short s_px[8][512];     // 8 KB  [pair][row*32 + blk'*8 + off]
    __shared__ float s_ds[2][128];              // norm partials / denom halves

    const int tid = threadIdx.x;
    const int w = tid >> 6, lane = tid & 63, l15 = lane & 15, q = lane >> 4;
    const int pr = w >> 1, e = w & 1;
    const int prow0 = blockIdx.x * BM + pr * 16;   // pair's 16 S-rows
    const int swz = l15 & 7;

    // ---- prologue: this wave loads its pair's 16 rows x its 256-d half
    const float* xrow = x + (size_t)(prow0 + l15) * D_DIM + e * 256 + q * 8;
    float4 va[8], vb[8];
    float ss = 0.f;
    #pragma unroll
    for (int kt = 0; kt < 8; ++kt) {
        va[kt] = *(const float4*)(xrow + kt * 32);
        vb[kt] = *(const float4*)(xrow + kt * 32 + 4);
        ss += va[kt].x*va[kt].x + va[kt].y*va[kt].y + va[kt].z*va[kt].z + va[kt].w*va[kt].w;
        ss += vb[kt].x*vb[kt].x + vb[kt].y*vb[kt].y + vb[kt].z*vb[kt].z + vb[kt].w*vb[kt].w;
    }
    ss += __shfl_xor(ss, 16, 64);
    ss += __shfl_xor(ss, 32, 64);

    // preload tile 0 -> buffer 0 (async global->LDS, 16B/lane; 2 calls each)
    #pragma unroll
    for (int k = 0; k < 2; ++k) {
        glds16(rm_sw + (size_t)(k * 1024 + tid) * 8, &s_rm[0][(k * 1024 + tid) * 8]);
        glds16(t_sw  + (size_t)(k * 1024 + tid) * 8, &s_ct[0][(k * 1024 + tid) * 8]);
    }
    if (lane < 16) s_ds[e][pr * 16 + l15] = ss;
    __syncthreads();                             // norm partials visible + preload drained
    const float tot = s_ds[0][pr * 16 + l15] + s_ds[1][pr * 16 + l15];
    const float scale = 1.0f / (fmaxf(sqrtf(tot), 1e-12f) * TAU);

    bf16x8 afrag[8];                             // B-frags: 16 pair rows x d-half e
    #pragma unroll
    for (int kt = 0; kt < 8; ++kt) {
        bf16x8 f;
        f[0] = (short)f2bf(va[kt].x * scale); f[1] = (short)f2bf(va[kt].y * scale);
        f[2] = (short)f2bf(va[kt].z * scale); f[3] = (short)f2bf(va[kt].w * scale);
        f[4] = (short)f2bf(vb[kt].x * scale); f[5] = (short)f2bf(vb[kt].y * scale);
        f[6] = (short)f2bf(vb[kt].z * scale); f[7] = (short)f2bf(vb[kt].w * scale);
        afrag[kt] = f;
    }

    f32x4 acc[16];
    #pragma unroll
    for (int nt = 0; nt < 16; ++nt) acc[nt] = (f32x4){0.f,0.f,0.f,0.f};
    float dsum = 0.f;

    const int blkw = (((e * 2 + (q >> 1)) ^ (l15 & 3)) * 8) + (q & 1) * 4;  // px write (u16)
    const int blkr = (q ^ (l15 & 3)) * 8;                                   // px read (u16)
    unsigned short* pxp = &s_px[pr][0];
    float* sxw = &s_sx[pr][e ^ 1][lane * 4];
    const float* sxr = &s_sx[pr][e][lane * 4];

    for (int j = 0; j < NKT; ++j) {
        const int p = j & 1;
        const size_t nb = (size_t)((j + 1) & (NKT - 1)) * 16384;
        // prefetch next tile into the other buffer; drains at B2 (full __syncthreads)
        #pragma unroll
        for (int k = 0; k < 2; ++k) {
            glds16(rm_sw + nb + (size_t)(k * 1024 + tid) * 8, &s_rm[p ^ 1][(k * 1024 + tid) * 8]);
            glds16(t_sw  + nb + (size_t)(k * 1024 + tid) * 8, &s_ct[p ^ 1][(k * 1024 + tid) * 8]);
        }

        const unsigned short* srm = s_rm[p];
        // ---- QK phase 1: OTHER cb-half (for the partner) over own d-half
        f32x4 t0 = (f32x4){0.f,0.f,0.f,0.f};
        const int cbo = ((e ^ 1) * 16 + l15) * 64;
        __builtin_amdgcn_s_setprio(1);
        #pragma unroll
        for (int kt = 0; kt < 8; ++kt) {
            int dc = (e * 32 + kt * 4 + q) ^ swz;
            bf16x8 bb = *(const bf16x8*)&srm[(cbo + dc) * 8];
            t0 = __builtin_amdgcn_mfma_f32_16x16x32_bf16(bb, afrag[kt], t0, 0, 0, 0);
        }
        __builtin_amdgcn_s_setprio(0);
        *(f32x4*)sxw = t0;                       // -> partner

        // ---- QK phase 2: OWN cb-half
        f32x4 u0 = (f32x4){0.f,0.f,0.f,0.f};
        const int cbe = (e * 16 + l15) * 64;
        __builtin_amdgcn_s_setprio(1);
        #pragma unroll
        for (int kt = 0; kt < 8; ++kt) {
            int dc = (e * 32 + kt * 4 + q) ^ swz;
            bf16x8 bb = *(const bf16x8*)&srm[(cbe + dc) * 8];
            u0 = __builtin_amdgcn_mfma_f32_16x16x32_bf16(bb, afrag[kt], u0, 0, 0, 0);
        }
        __builtin_amdgcn_s_setprio(0);
        barrier_lgkm();                          // Bsx: partials visible (prefetch in flight)

        const f32x4 r0 = *(const f32x4*)sxr;
        // ---- full-d S for own cb-half; P = exp
        const float pA0 = __expf(u0[0] + r0[0]), pA1 = __expf(u0[1] + r0[1]);
        const float pA2 = __expf(u0[2] + r0[2]), pA3 = __expf(u0[3] + r0[3]);
        float loc = (pA0 + pA1) + (pA2 + pA3);
        float tA = loc; pl16swapf(loc, tA); loc += tA;
        float uA = loc; pl32swapf(loc, uA); loc += uA;
        dsum += loc;                             // half-sum (own cb-half), row l15

        // ---- pack + swizzled scatter to px: P[row l15][cb e*16+4q .. +3]
        uint2 wA; wA.x = cvtpk(pA0, pA1); wA.y = cvtpk(pA2, pA3);
        *(uint2*)&pxp[l15 * 32 + blkw] = wA;
        barrier_lgkm();                          // B1: px visible (prefetch in flight)

        bf16x8 ap0 = *(const bf16x8*)&pxp[l15 * 32 + blkr];   // P[l15][8q..8q+7]

        // ---- O += P · C_tile over this wave's d-half
        const unsigned short* sct = s_ct[p];
        __builtin_amdgcn_s_setprio(1);
        #pragma unroll
        for (int nt = 0; nt < 16; ++nt) {
            int dd = e * 256 + nt * 16 + l15;
            int c = (dd * 4 + q) ^ ((dd >> 1) & 7);
            bf16x8 bt = *(const bf16x8*)&sct[c * 8];
            acc[nt] = __builtin_amdgcn_mfma_f32_16x16x32_bf16(ap0, bt, acc[nt], 0, 0, 0);
        }
        __builtin_amdgcn_s_setprio(0);
        __syncthreads();                         // B2: buf reads done + prefetch drained
    }

    // ---- epilogue: combine denominator halves across the pair, divide, store
    if (lane < 16) s_ds[e][pr * 16 + l15] = dsum;
    __syncthreads();
    float* ob = out + (size_t)prow0 * D_DIM + e * 256 + l15;
    #pragma unroll
    for (int r = 0; r < 4; ++r) {
        int rl = pr * 16 + q * 4 + r;
        float inv = 1.0f / (s_ds[0][rl] + s_ds[1][rl]);
        #pragma unroll
        for (int nt = 0; nt < 16; ++nt) {
            ob[(size_t)(q * 4 + r) * D_DIM + nt * 16] = acc[nt][r] * inv;
        }
    }
}

extern "C" void kernel_launch(void* const* d_in, const int* in_sizes, int n_in,
                              void* d_out, int out_size, void* d_ws, size_t ws_size,
                              hipStream_t stream) {
    const float* x  = (const float*)d_in[0];
    const float* cb = (const float*)d_in[1];
    unsigned short* rm_sw = (unsigned short*)d_ws;                       // 8 MB
    unsigned short* t_sw  = rm_sw + (size_t)K_CB * D_DIM;                // 8 MB
    float* outp = (float*)d_out;

    prep_codebook<<<NKT, 512, 0, stream>>>(cb, rm_sw, t_sw);
    cbmap_main<<<N_ROWS / BM, 1024, 0, stream>>>(x, rm_sw, t_sw, outp);
}